// Round 1
// 202.830 us; speedup vs baseline: 1.0529x; 1.0529x over previous
//
#include <hip/hip_runtime.h>

// NonLocalBlock: B=4, C=256, Ci=128, H=W=64, N=4096.
// R10: k_attn rewritten as swapped-QK 32x32x16 with in-register softmax
// (cvt_pkrtz + permlane32_swap, T12/m214 recipe). R9 counters showed k_attn
// LDS-pipe-bound (68 LDS ops vs 64 MFMA per jt-wave, MfmaUtil 21%): the Wl
// LDS round-trip (32 ds_write_b16 + 4 ds_read_b128/jt) existed only to
// re-layout exp(f) from D-layout to A-layout. Swapped QK makes j lane-local
// so the relayout is 16 cvt_pk + 8 permlane32_swap in registers. 32x32 MFMA
// also cuts MFMA-pipe time 17% (2495 vs 2075 TF ceiling). LDS 73->64 KB.
// All other kernels unchanged from R9.

#define B_  4
#define C_  256
#define CI  128
#define N_  4096
#define NB  (B_*N_)     // 16384
#define ISPLIT 16
#define MB_ (1u<<20)

typedef _Float16 f16;
typedef f16   f16x8 __attribute__((ext_vector_type(8)));
typedef f16   f16x4 __attribute__((ext_vector_type(4)));
typedef float f32x4 __attribute__((ext_vector_type(4)));
typedef float f32x16 __attribute__((ext_vector_type(16)));
typedef unsigned u32x2 __attribute__((ext_vector_type(2)));
typedef unsigned u32x4v __attribute__((ext_vector_type(4)));

#define MFMA(a,b,c)   __builtin_amdgcn_mfma_f32_16x16x32_f16(a,b,c,0,0,0)
#define MFMA32(a,b,c) __builtin_amdgcn_mfma_f32_32x32x16_f16(a,b,c,0,0,0)

// async global->LDS, 16B per lane; LDS dest = wave-uniform base + lane*16
#define GLD16(g, lp) __builtin_amdgcn_global_load_lds( \
    (const __attribute__((address_space(1))) void*)(g), \
    (__attribute__((address_space(3))) void*)(lp), 16, 0, 0)

// ---- workspace byte offsets (~30 MB) ----
#define OFF_THETA  0                 // f16 [B][N][CI]  4 MB
#define OFF_PHI    (4u*MB_)          // f16 [B][N][CI]  4 MB
#define OFF_G      (8u*MB_)          // f16 [B][CI][N]  4 MB
#define OFF_YP     (12u*MB_)         // f16 [4][B][N][CI]  16 MB (j-quarter partials)
#define OFF_WY     0                 // f16 [B][C][N] 8 MB — overlays theta+phi (dead by k_wz)
#define OFF_MD     (28u*MB_)                  // f32 [NB] log D  (64 KB)
#define OFF_PS     (OFF_MD + 65536)           // f32 [ISPLIT][NB]  1 MB
#define OFF_PSUM   (OFF_PS + ISPLIT*NB*4)     // f32 [256][2][256]  512 KB
#define OFF_SSUM   (OFF_PSUM + 524288)
#define OFF_SSQ    (OFF_SSUM + 1024)
#define OFF_WCVT   (OFF_SSQ + 1024)           // f16 weights g,t,p,z  256 KB
#define PSZ ((size_t)B_*N_*CI)

// ---------------- init: weight cvt f32->f16 ----------------
__global__ void k_init(const float* gw, const float* tw, const float* pw,
                       const float* zw, f16* wcvt) {
    int i = blockIdx.x * 256 + threadIdx.x;          // 0..131071
    const float* s;
    int which = i >> 15;
    if (which == 0) s = gw; else if (which == 1) s = tw;
    else if (which == 2) s = pw; else s = zw;
    wcvt[i] = (f16)s[i & 32767];
}

// ---------------- fused 1x1-conv projections (all 3, one x read) ----------------
__global__ __launch_bounds__(256) void k_proj(
        const float* __restrict__ x, const f16* __restrict__ wcvt,
        const float* __restrict__ gb, const float* __restrict__ tb,
        const float* __restrict__ pb,
        f16* __restrict__ thetaT, f16* __restrict__ phiT, f16* __restrict__ gC) {
    __shared__ __align__(16) f16 xT[32 * 264];       // [n][c], stride 264
    int bb = blockIdx.x >> 7;
    int n0 = (blockIdx.x & 127) * 32;
    int t = threadIdx.x;

    const float* xb = x + (size_t)bb * C_ * N_;
    for (int rep = 0; rep < 8; rep++) {
        int lin = rep * 256 + t;
        int c = lin >> 3, np = (lin & 7) * 4;
        float4 v = *reinterpret_cast<const float4*>(xb + c * N_ + n0 + np);
        xT[(np + 0) * 264 + c] = (f16)v.x;
        xT[(np + 1) * 264 + c] = (f16)v.y;
        xT[(np + 2) * 264 + c] = (f16)v.z;
        xT[(np + 3) * 264 + c] = (f16)v.w;
    }
    __syncthreads();

    int w = t >> 6, l16 = t & 15, q = (t & 63) >> 4;
    int ci0 = w * 32;
    for (int proj = 0; proj < 3; proj++) {
        const f16* W0 = wcvt + proj * 32768;         // [128][256] f16 row-major
        f32x4 acc[2][2] = {};
        for (int kk = 0; kk < 8; kk++) {
            f16x8 a0 = *reinterpret_cast<const f16x8*>(W0 + (ci0 + l16) * 256 + kk * 32 + q * 8);
            f16x8 a1 = *reinterpret_cast<const f16x8*>(W0 + (ci0 + 16 + l16) * 256 + kk * 32 + q * 8);
#pragma unroll
            for (int nt = 0; nt < 2; nt++) {
                f16x8 bv = *reinterpret_cast<const f16x8*>(&xT[(nt * 16 + l16) * 264 + kk * 32 + q * 8]);
                acc[0][nt] = MFMA(a0, bv, acc[0][nt]);
                acc[1][nt] = MFMA(a1, bv, acc[1][nt]);
            }
        }
        const float* bias = (proj == 0) ? gb : (proj == 1) ? tb : pb;
#pragma unroll
        for (int a = 0; a < 2; a++) {
#pragma unroll
            for (int nt = 0; nt < 2; nt++) {
                int n = n0 + nt * 16 + l16;
                int cib = ci0 + a * 16 + q * 4;
                if (proj == 0) {
#pragma unroll
                    for (int r = 0; r < 4; r++)
                        gC[((size_t)bb * CI + cib + r) * N_ + n] = (f16)(acc[a][nt][r] + bias[cib + r]);
                } else {
                    f16x4 v4;
#pragma unroll
                    for (int r = 0; r < 4; r++) v4[r] = (f16)(acc[a][nt][r] + bias[cib + r]);
                    f16* dst = (proj == 1 ? thetaT : phiT) + ((size_t)bb * N_ + n) * CI + cib;
                    *reinterpret_cast<f16x4*>(dst) = v4;
                }
            }
        }
    }
}

// ---------------- pass 2: column exp-sums, plain ps writes ----------------
// grid 1024 = bb(4) x jb(16) x isp(16); i-slice 256 = 4 staged tiles of 64.
__global__ __launch_bounds__(256, 2) void k_cols(
        const f16* __restrict__ thetaT, const f16* __restrict__ phiT,
        float* __restrict__ ps) {
    __shared__ __align__(16) f16 thS[2][64 * 128];
    int id = blockIdx.x;                 // 1024
    int isp = id & 15, jb = (id >> 4) & 15, bb = id >> 8;
    int t = threadIdx.x, w = t >> 6, l = t & 63, l16 = t & 15, q = (t & 63) >> 4;
    int jw0 = jb * 256 + w * 64;

    f16x8 pf[4][4];
    const f16* pb = phiT + ((size_t)bb * N_ + jw0) * CI;
#pragma unroll
    for (int jt = 0; jt < 4; jt++)
#pragma unroll
        for (int kk = 0; kk < 4; kk++)
            pf[jt][kk] = *reinterpret_cast<const f16x8*>(pb + (jt * 16 + l16) * CI + kk * 32 + q * 8);

    const f16* thB = thetaT + ((size_t)bb * N_ + isp * 256) * CI;
    auto stage = [&](int bf, int it0) {
#pragma unroll
        for (int r = 0; r < 4; r++) {
            int p = r * 256 + w * 64 + l;
            int pi = p >> 4, pu = (p & 15) ^ (pi & 15);
            const char* ga = (const char*)(thB + (size_t)(it0 + pi) * CI) + pu * 16;
            GLD16(ga, &thS[bf][(r * 256 + w * 64) * 8]);
        }
    };

    float s[4] = {0.f, 0.f, 0.f, 0.f};
    stage(0, 0);
    __syncthreads();
    for (int it = 0; it < 4; it++) {
        int bf = it & 1;
        if (it + 1 < 4) stage(bf ^ 1, (it + 1) * 64);
#pragma unroll
        for (int ic = 0; ic < 4; ic++) {
            f16x8 av[4];
#pragma unroll
            for (int kk = 0; kk < 4; kk++)
                av[kk] = *reinterpret_cast<const f16x8*>(
                    &thS[bf][(ic * 16 + l16) * 128 + (((kk * 4 + q) ^ l16) * 8)]);
            f32x4 f[4] = {};
#pragma unroll
            for (int kk = 0; kk < 4; kk++)
#pragma unroll
                for (int jt = 0; jt < 4; jt++)
                    f[jt] = MFMA(av[kk], pf[jt][kk], f[jt]);
#pragma unroll
            for (int jt = 0; jt < 4; jt++)
                s[jt] += __expf(f[jt][0]) + __expf(f[jt][1])
                       + __expf(f[jt][2]) + __expf(f[jt][3]);
        }
        __syncthreads();
    }
#pragma unroll
    for (int jt = 0; jt < 4; jt++) {
        s[jt] += __shfl_xor(s[jt], 16);
        s[jt] += __shfl_xor(s[jt], 32);
    }
    if (q == 0) {
#pragma unroll
        for (int jt = 0; jt < 4; jt++)
            ps[isp * NB + bb * N_ + jw0 + jt * 16 + l16] = s[jt];
    }
}

// ---------------- merge: md[j] = log(sum_isp ps) ----------------
__global__ void k_colmerge(const float* __restrict__ ps, float* __restrict__ md) {
    int j = blockIdx.x * 256 + threadIdx.x;          // 0..16383
    float s = 0.f;
    for (int isp = 0; isp < ISPLIT; isp++) s += ps[isp * NB + j];
    md[j] = __logf(s);
}

// ---------------- pass 3: y = softmax(f) @ g  (swapped-QK 32x32, in-reg softmax) --
// Per block: 4 waves x 32 i-rows = 128 i, one j-quarter (1024 j, 16 tiles of 64).
// QK: f' = MFMA32(phi, theta) -> D: col(lane&31)=i, row((r&3)+8(r>>2)+4hi)=j.
// Softmax axis j is lane-local; W A-frags built with cvt_pkrtz+permlane32_swap
// (no LDS round-trip). PV: y = MFMA32(Wfrag, gfrag). LDS ops/jt-wave: 68 -> 32.
__global__ __launch_bounds__(256, 2) void k_attn(
        const f16* __restrict__ thetaT, const f16* __restrict__ phiT,
        const f16* __restrict__ gC, const float* __restrict__ md,
        f16* __restrict__ yP) {
    __shared__ __align__(16) char smem[65536];
    f16 (*phiS)[64 * 128] = (f16(*)[64 * 128])smem;            // 2 x 16 KB [j][ci]
    f16 (*gS)[128 * 64]   = (f16(*)[128 * 64])(smem + 32768);  // 2 x 16 KB [ci][j]
    f16* yTr = (f16*)smem;                                     // epilogue overlay

    int jq = blockIdx.x & 3;
    int ib = blockIdx.x >> 2;          // 0..127
    int bb = ib >> 5;
    int i0 = (ib & 31) * 128;
    int t = threadIdx.x, w = t >> 6, l = t & 63;
    int l31 = l & 31, hi = l >> 5;
    int jbase = jq * 1024;

    // theta B-fragments (K=128 -> 8 kk of 16): B[n=i][k]; lane n=l31, k=hi*8+e
    f16x8 ta[8];
    const f16* tb = thetaT + ((size_t)bb * N_ + i0 + w * 32 + l31) * CI + hi * 8;
#pragma unroll
    for (int kk = 0; kk < 8; kk++)
        ta[kk] = *reinterpret_cast<const f16x8*>(tb + kk * 16);

    const f16* phiB = phiT + (size_t)bb * N_ * CI;
    const f16* gB   = gC   + (size_t)bb * CI * N_;
    const float* mdb = md + bb * N_;

    auto stage = [&](int bf, int j0g) {
#pragma unroll
        for (int r = 0; r < 4; r++) {
            int p = r * 256 + w * 64 + l;
            int ub = (r * 256 + w * 64) * 8;          // wave-uniform LDS base (f16)
            int pj = p >> 4, pu = (p & 15) ^ (pj & 15);
            const char* ga = (const char*)(phiB + (size_t)(j0g + pj) * CI) + pu * 16;
            GLD16(ga, &phiS[bf][ub]);
            int pc = p >> 3, pu2 = (p & 7) ^ (pc & 7);
            const char* ga2 = (const char*)(gB + (size_t)pc * N_ + j0g) + pu2 * 16;
            GLD16(ga2, &gS[bf][ub]);
        }
    };

    f32x16 yacc[4] = {};                 // [cs]: y[i 32][ci = cs*32+l31]
    stage(0, jbase);
    __syncthreads();
    for (int jt = 0; jt < 16; jt++) {
        int bf = jt & 1;
        if (jt + 1 < 16) stage(bf ^ 1, jbase + (jt + 1) * 64);

        // md for this jt: mdv[js][r] = md[jbase+jt*64+js*32+(r&3)+8*(r>>2)+4*hi]
        float mdv[2][16];
#pragma unroll
        for (int js = 0; js < 2; js++)
#pragma unroll
            for (int c = 0; c < 4; c++) {
                float4 v = *reinterpret_cast<const float4*>(
                    mdb + jbase + jt * 64 + js * 32 + c * 8 + hi * 4);
                mdv[js][c * 4 + 0] = v.x; mdv[js][c * 4 + 1] = v.y;
                mdv[js][c * 4 + 2] = v.z; mdv[js][c * 4 + 3] = v.w;
            }

        // QK: facc[js][r] = f[i=l31][j = js*32 + (r&3)+8*(r>>2)+4*hi]
        f32x16 facc[2] = {};
#pragma unroll
        for (int kk = 0; kk < 8; kk++) {
#pragma unroll
            for (int js = 0; js < 2; js++) {
                f16x8 pv = *reinterpret_cast<const f16x8*>(
                    &phiS[bf][(js * 32 + l31) * 128 + (((kk * 2 + hi) ^ (l31 & 15)) * 8)]);
                facc[js] = MFMA32(pv, ta[kk], facc[js]);
            }
        }

        // softmax + in-register relayout to PV A-frags, then PV
#pragma unroll
        for (int js = 0; js < 2; js++) {
#pragma unroll
            for (int ch = 0; ch < 2; ch++) {
                float e0 = __expf(facc[js][ch * 8 + 0] - mdv[js][ch * 8 + 0]);
                float e1 = __expf(facc[js][ch * 8 + 1] - mdv[js][ch * 8 + 1]);
                float e2 = __expf(facc[js][ch * 8 + 2] - mdv[js][ch * 8 + 2]);
                float e3 = __expf(facc[js][ch * 8 + 3] - mdv[js][ch * 8 + 3]);
                float e4 = __expf(facc[js][ch * 8 + 4] - mdv[js][ch * 8 + 4]);
                float e5 = __expf(facc[js][ch * 8 + 5] - mdv[js][ch * 8 + 5]);
                float e6 = __expf(facc[js][ch * 8 + 6] - mdv[js][ch * 8 + 6]);
                float e7 = __expf(facc[js][ch * 8 + 7] - mdv[js][ch * 8 + 7]);
                unsigned p01 = __builtin_bit_cast(unsigned, __builtin_amdgcn_cvt_pkrtz(e0, e1));
                unsigned p23 = __builtin_bit_cast(unsigned, __builtin_amdgcn_cvt_pkrtz(e2, e3));
                unsigned p45 = __builtin_bit_cast(unsigned, __builtin_amdgcn_cvt_pkrtz(e4, e5));
                unsigned p67 = __builtin_bit_cast(unsigned, __builtin_amdgcn_cvt_pkrtz(e6, e7));
                u32x2 s0 = __builtin_amdgcn_permlane32_swap(p01, p45, false, false);
                u32x2 s1 = __builtin_amdgcn_permlane32_swap(p23, p67, false, false);
                u32x4v wu = {s0[0], s1[0], s0[1], s1[1]};
                f16x8 wfr = __builtin_bit_cast(f16x8, wu);   // A[m=i=l31][k=hi*8+e]
                int jc = js * 2 + ch;                        // 16-j chunk index
#pragma unroll
                for (int cs = 0; cs < 4; cs++) {
                    f16x8 gv = *reinterpret_cast<const f16x8*>(
                        &gS[bf][(cs * 32 + l31) * 64 + (((jc * 2 + hi) ^ (l31 & 7)) * 8)]);
                    yacc[cs] = MFMA32(wfr, gv, yacc[cs]);
                }
            }
        }
        __syncthreads();
    }

    // epilogue: yacc[cs][r] = y[i=(r&3)+8*(r>>2)+4*hi][ci=cs*32+l31]
    f16* yw = yTr + w * (32 * 136);
#pragma unroll
    for (int cs = 0; cs < 4; cs++)
#pragma unroll
        for (int r = 0; r < 16; r++)
            yw[((r & 3) + 8 * (r >> 2) + 4 * hi) * 136 + cs * 32 + l31] = (f16)yacc[cs][r];
    f16* yo = yP + (size_t)jq * PSZ + ((size_t)bb * N_ + i0 + w * 32) * CI;
#pragma unroll
    for (int rr = 0; rr < 8; rr++) {
        int chunk = rr * 64 + l;
        int il = chunk >> 4, u = chunk & 15;
        *reinterpret_cast<f16x8*>(yo + il * CI + u * 8) =
            *reinterpret_cast<const f16x8*>(&yw[il * 136 + u * 8]);
    }
}

// ---------------- pass 4: w_y = wz @ (sum of y partials) + b ----------------
// grid 256: block = bb(4) x nb(64 n-tiles of 64); reads its yP slice ONCE,
// computes all 256 output channels; per-block channel partials -> psum.
__global__ __launch_bounds__(256) void k_wz(
        const f16* __restrict__ wzc, const f16* __restrict__ yP,
        const float* __restrict__ zb, f16* __restrict__ wy,
        float* __restrict__ psum) {
    int id = blockIdx.x;                  // 256
    int nb = id & 63, bb = id >> 6;
    int t = threadIdx.x, w = t >> 6, l16 = t & 15, q = (t & 63) >> 4;
    int o0 = w * 64, n0 = nb * 64;
    f32x4 acc[4][4] = {};                 // [os][nt]
#pragma unroll
    for (int kk = 0; kk < 4; kk++) {
        f16x8 bv[4];
#pragma unroll
        for (int nt = 0; nt < 4; nt++) {
            size_t yi = ((size_t)bb * N_ + n0 + nt * 16 + l16) * CI + kk * 32 + q * 8;
            f16x8 b0 = *reinterpret_cast<const f16x8*>(yP + yi);
            f16x8 b1 = *reinterpret_cast<const f16x8*>(yP + PSZ + yi);
            f16x8 b2 = *reinterpret_cast<const f16x8*>(yP + 2 * PSZ + yi);
            f16x8 b3 = *reinterpret_cast<const f16x8*>(yP + 3 * PSZ + yi);
            bv[nt] = (b0 + b1) + (b2 + b3);
        }
#pragma unroll
        for (int os = 0; os < 4; os++) {
            f16x8 av = *reinterpret_cast<const f16x8*>(
                wzc + (o0 + os * 16 + l16) * CI + kk * 32 + q * 8);
#pragma unroll
            for (int nt = 0; nt < 4; nt++)
                acc[os][nt] = MFMA(av, bv[nt], acc[os][nt]);
        }
    }
#pragma unroll
    for (int os = 0; os < 4; os++)
#pragma unroll
    for (int r = 0; r < 4; r++) {
        int o = o0 + os * 16 + q * 4 + r;
        float bias = zb[o];
        float sr = 0.f, qr = 0.f;
#pragma unroll
        for (int nt = 0; nt < 4; nt++) {
            float v = acc[os][nt][r] + bias;
            wy[((size_t)bb * C_ + o) * N_ + n0 + nt * 16 + l16] = (f16)v;
            sr += v; qr += v * v;
        }
#pragma unroll
        for (int off = 1; off < 16; off <<= 1) {
            sr += __shfl_xor(sr, off);
            qr += __shfl_xor(qr, off);
        }
        if (l16 == 0) {
            psum[(o * 2 + 0) * 256 + id] = sr;
            psum[(o * 2 + 1) * 256 + id] = qr;
        }
    }
}

// ---------------- reduce psum -> ssum/ssq ----------------
__global__ void k_red(const float* __restrict__ psum, float* __restrict__ ssum,
                      float* __restrict__ ssq) {
    int b = blockIdx.x;                   // 0: ssum, 1: ssq
    int o = threadIdx.x;
    const float* src = psum + (o * 2 + b) * 256;
    float s = 0.f;
    for (int k = 0; k < 64; k++) {
        float4 v = reinterpret_cast<const float4*>(src)[k];
        s += v.x + v.y + v.z + v.w;
    }
    (b == 0 ? ssum : ssq)[o] = s;
}

// ---------------- pass 5: BN (stats inline) + residual ----------------
__global__ void k_final(const f16* __restrict__ wy, const float* __restrict__ x,
                        const float* __restrict__ ssum, const float* __restrict__ ssq,
                        const float* __restrict__ gamma, const float* __restrict__ beta,
                        float* __restrict__ out) {
    int p = blockIdx.x * 256 + threadIdx.x;           // 512K groups of 8
    int c = (p >> 9) & 255;
    const float inv = 1.0f / 16384.0f;
    float mean = ssum[c] * inv;
    float var = ssq[c] * inv - mean * mean;
    float s = gamma[c] * rsqrtf(var + 1e-5f);
    float h = beta[c] - mean * s;
    f16x8 wv = reinterpret_cast<const f16x8*>(wy)[p];
    float4 x0 = reinterpret_cast<const float4*>(x)[2 * p];
    float4 x1 = reinterpret_cast<const float4*>(x)[2 * p + 1];
    float4 o0, o1;
    o0.x = (float)wv[0] * s + h + x0.x;
    o0.y = (float)wv[1] * s + h + x0.y;
    o0.z = (float)wv[2] * s + h + x0.z;
    o0.w = (float)wv[3] * s + h + x0.w;
    o1.x = (float)wv[4] * s + h + x1.x;
    o1.y = (float)wv[5] * s + h + x1.y;
    o1.z = (float)wv[6] * s + h + x1.z;
    o1.w = (float)wv[7] * s + h + x1.w;
    reinterpret_cast<float4*>(out)[2 * p] = o0;
    reinterpret_cast<float4*>(out)[2 * p + 1] = o1;
}

extern "C" void kernel_launch(void* const* d_in, const int* in_sizes, int n_in,
                              void* d_out, int out_size, void* d_ws, size_t ws_size,
                              hipStream_t stream) {
    const float* x     = (const float*)d_in[0];
    const float* gw    = (const float*)d_in[1];
    const float* gb    = (const float*)d_in[2];
    const float* tw    = (const float*)d_in[3];
    const float* tbv   = (const float*)d_in[4];
    const float* pw    = (const float*)d_in[5];
    const float* pb    = (const float*)d_in[6];
    const float* zw    = (const float*)d_in[7];
    const float* zb    = (const float*)d_in[8];
    const float* gamma = (const float*)d_in[9];
    const float* beta  = (const float*)d_in[10];

    char* ws = (char*)d_ws;
    f16* thetaT = (f16*)(ws + OFF_THETA);
    f16* phiT   = (f16*)(ws + OFF_PHI);
    f16* gC     = (f16*)(ws + OFF_G);
    f16* yP     = (f16*)(ws + OFF_YP);
    f16* wy     = (f16*)(ws + OFF_WY);
    f16* wcvt   = (f16*)(ws + OFF_WCVT);
    float* md   = (float*)(ws + OFF_MD);
    float* ps   = (float*)(ws + OFF_PS);
    float* psum = (float*)(ws + OFF_PSUM);
    float* ssum = (float*)(ws + OFF_SSUM);
    float* ssq  = (float*)(ws + OFF_SSQ);

    k_init<<<512, 256, 0, stream>>>(gw, tw, pw, zw, wcvt);
    k_proj<<<512, 256, 0, stream>>>(x, wcvt, gb, tbv, pb, thetaT, phiT, gC);
    k_cols<<<1024, 256, 0, stream>>>(thetaT, phiT, ps);
    k_colmerge<<<64, 256, 0, stream>>>(ps, md);
    k_attn<<<512, 256, 0, stream>>>(thetaT, phiT, gC, md, yP);
    k_wz<<<256, 256, 0, stream>>>(wcvt + 3 * 32768, yP, zb, wy, psum);
    k_red<<<2, 256, 0, stream>>>(psum, ssum, ssq);
    k_final<<<2048, 256, 0, stream>>>(wy, x, ssum, ssq, gamma, beta, (float*)d_out);
}

// Round 2
// 201.009 us; speedup vs baseline: 1.0624x; 1.0091x over previous
//
#include <hip/hip_runtime.h>

// NonLocalBlock: B=4, C=256, Ci=128, H=W=64, N=4096.
// R11: (1) k_cols rewritten to 32x32 swapped-operand (col j lane-local ->
// in-lane exp-sum, half the MFMA insts, grid 2048 thin-wave for 4 waves/SIMD).
// (2) exp->exp2 pipeline-wide: theta scaled by log2(e) in k_proj, k_colmerge
// stores -log2(D), k_attn preloads it as the MFMA C-operand (subtract folded
// into accumulate) and uses raw v_exp_f32. (3) T5 s_setprio around MFMA
// clusters in k_attn/k_cols (2-resident-block role-split regime).
// R10 post-mortem: k_attn 61.4->45.4us, MfmaUtil 21->29%; pipes run serially
// (6.8K cyc/jt = sum of MFMA 2.2K + LDS 2.4K + VALU 1K), hence T5 + VALU cuts.

#define B_  4
#define C_  256
#define CI  128
#define N_  4096
#define NB  (B_*N_)     // 16384
#define ISPLIT 16
#define MB_ (1u<<20)
#define LOG2E 1.442695041f

typedef _Float16 f16;
typedef f16   f16x8 __attribute__((ext_vector_type(8)));
typedef f16   f16x4 __attribute__((ext_vector_type(4)));
typedef float f32x4 __attribute__((ext_vector_type(4)));
typedef float f32x16 __attribute__((ext_vector_type(16)));
typedef unsigned u32x2 __attribute__((ext_vector_type(2)));
typedef unsigned u32x4v __attribute__((ext_vector_type(4)));

#define MFMA(a,b,c)   __builtin_amdgcn_mfma_f32_16x16x32_f16(a,b,c,0,0,0)
#define MFMA32(a,b,c) __builtin_amdgcn_mfma_f32_32x32x16_f16(a,b,c,0,0,0)

// async global->LDS, 16B per lane; LDS dest = wave-uniform base + lane*16
#define GLD16(g, lp) __builtin_amdgcn_global_load_lds( \
    (const __attribute__((address_space(1))) void*)(g), \
    (__attribute__((address_space(3))) void*)(lp), 16, 0, 0)

// ---- workspace byte offsets (~30 MB) ----
#define OFF_THETA  0                 // f16 [B][N][CI]  4 MB (pre-scaled by log2e)
#define OFF_PHI    (4u*MB_)          // f16 [B][N][CI]  4 MB
#define OFF_G      (8u*MB_)          // f16 [B][CI][N]  4 MB
#define OFF_YP     (12u*MB_)         // f16 [4][B][N][CI]  16 MB (j-quarter partials)
#define OFF_WY     0                 // f16 [B][C][N] 8 MB — overlays theta+phi (dead by k_wz)
#define OFF_MD     (28u*MB_)                  // f32 [NB]  -log2(D)  (64 KB)
#define OFF_PS     (OFF_MD + 65536)           // f32 [ISPLIT][NB]  1 MB
#define OFF_PSUM   (OFF_PS + ISPLIT*NB*4)     // f32 [256][2][256]  512 KB
#define OFF_SSUM   (OFF_PSUM + 524288)
#define OFF_SSQ    (OFF_SSUM + 1024)
#define OFF_WCVT   (OFF_SSQ + 1024)           // f16 weights g,t,p,z  256 KB
#define PSZ ((size_t)B_*N_*CI)

// ---------------- init: weight cvt f32->f16 ----------------
__global__ void k_init(const float* gw, const float* tw, const float* pw,
                       const float* zw, f16* wcvt) {
    int i = blockIdx.x * 256 + threadIdx.x;          // 0..131071
    const float* s;
    int which = i >> 15;
    if (which == 0) s = gw; else if (which == 1) s = tw;
    else if (which == 2) s = pw; else s = zw;
    wcvt[i] = (f16)s[i & 32767];
}

// ---------------- fused 1x1-conv projections (all 3, one x read) ----------------
__global__ __launch_bounds__(256) void k_proj(
        const float* __restrict__ x, const f16* __restrict__ wcvt,
        const float* __restrict__ gb, const float* __restrict__ tb,
        const float* __restrict__ pb,
        f16* __restrict__ thetaT, f16* __restrict__ phiT, f16* __restrict__ gC) {
    __shared__ __align__(16) f16 xT[32 * 264];       // [n][c], stride 264
    int bb = blockIdx.x >> 7;
    int n0 = (blockIdx.x & 127) * 32;
    int t = threadIdx.x;

    const float* xb = x + (size_t)bb * C_ * N_;
    for (int rep = 0; rep < 8; rep++) {
        int lin = rep * 256 + t;
        int c = lin >> 3, np = (lin & 7) * 4;
        float4 v = *reinterpret_cast<const float4*>(xb + c * N_ + n0 + np);
        xT[(np + 0) * 264 + c] = (f16)v.x;
        xT[(np + 1) * 264 + c] = (f16)v.y;
        xT[(np + 2) * 264 + c] = (f16)v.z;
        xT[(np + 3) * 264 + c] = (f16)v.w;
    }
    __syncthreads();

    int w = t >> 6, l16 = t & 15, q = (t & 63) >> 4;
    int ci0 = w * 32;
    for (int proj = 0; proj < 3; proj++) {
        const f16* W0 = wcvt + proj * 32768;         // [128][256] f16 row-major
        f32x4 acc[2][2] = {};
        for (int kk = 0; kk < 8; kk++) {
            f16x8 a0 = *reinterpret_cast<const f16x8*>(W0 + (ci0 + l16) * 256 + kk * 32 + q * 8);
            f16x8 a1 = *reinterpret_cast<const f16x8*>(W0 + (ci0 + 16 + l16) * 256 + kk * 32 + q * 8);
#pragma unroll
            for (int nt = 0; nt < 2; nt++) {
                f16x8 bv = *reinterpret_cast<const f16x8*>(&xT[(nt * 16 + l16) * 264 + kk * 32 + q * 8]);
                acc[0][nt] = MFMA(a0, bv, acc[0][nt]);
                acc[1][nt] = MFMA(a1, bv, acc[1][nt]);
            }
        }
        const float* bias = (proj == 0) ? gb : (proj == 1) ? tb : pb;
        float scl = (proj == 1) ? LOG2E : 1.0f;      // fold ln2 into theta
#pragma unroll
        for (int a = 0; a < 2; a++) {
#pragma unroll
            for (int nt = 0; nt < 2; nt++) {
                int n = n0 + nt * 16 + l16;
                int cib = ci0 + a * 16 + q * 4;
                if (proj == 0) {
#pragma unroll
                    for (int r = 0; r < 4; r++)
                        gC[((size_t)bb * CI + cib + r) * N_ + n] = (f16)(acc[a][nt][r] + bias[cib + r]);
                } else {
                    f16x4 v4;
#pragma unroll
                    for (int r = 0; r < 4; r++)
                        v4[r] = (f16)((acc[a][nt][r] + bias[cib + r]) * scl);
                    f16* dst = (proj == 1 ? thetaT : phiT) + ((size_t)bb * N_ + n) * CI + cib;
                    *reinterpret_cast<f16x4*>(dst) = v4;
                }
            }
        }
    }
}

// ---------------- pass 2: column exp-sums (32x32 swapped, lane-local j) ------
// grid 2048 = bb(4) x jb(32) x isp(16); i-slice 256 = 4 staged tiles of 64.
// D = MFMA32(theta_A, phi_B): col(lane&31)=j from B, rows=i from A -> each
// lane sums exp2 over its 16 i-rows in-register; one xor-32 shuffle at end.
__global__ __launch_bounds__(256, 4) void k_cols(
        const f16* __restrict__ thetaT, const f16* __restrict__ phiT,
        float* __restrict__ ps) {
    __shared__ __align__(16) f16 thS[2][64 * 128];
    int id = blockIdx.x;                 // 2048
    int isp = id & 15, jb = (id >> 4) & 31, bb = id >> 9;
    int t = threadIdx.x, w = t >> 6, l = t & 63;
    int l31 = l & 31, hi = l >> 5;
    int jw = jb * 128 + w * 32 + l31;    // this lane's j column

    // phi B-frags: B[k][n=j], lane n=l31, k = kk*16 + hi*8 + e
    f16x8 pf[8];
    const f16* pb = phiT + ((size_t)bb * N_ + jw) * CI + hi * 8;
#pragma unroll
    for (int kk = 0; kk < 8; kk++)
        pf[kk] = *reinterpret_cast<const f16x8*>(pb + kk * 16);

    const f16* thB = thetaT + ((size_t)bb * N_ + isp * 256) * CI;
    auto stage = [&](int bf, int it0) {
#pragma unroll
        for (int r = 0; r < 4; r++) {
            int p = r * 256 + w * 64 + l;
            int pi = p >> 4, pu = (p & 15) ^ (pi & 15);
            const char* ga = (const char*)(thB + (size_t)(it0 + pi) * CI) + pu * 16;
            GLD16(ga, &thS[bf][(r * 256 + w * 64) * 8]);
        }
    };

    float s = 0.f;
    stage(0, 0);
    __syncthreads();
    for (int it = 0; it < 4; it++) {
        int bf = it & 1;
        if (it + 1 < 4) stage(bf ^ 1, (it + 1) * 64);
#pragma unroll
        for (int it2 = 0; it2 < 2; it2++) {
            f16x8 av[8];
#pragma unroll
            for (int kk = 0; kk < 8; kk++)
                av[kk] = *reinterpret_cast<const f16x8*>(
                    &thS[bf][(it2 * 32 + l31) * 128 + (((kk * 2 + hi) ^ (l31 & 15)) * 8)]);
            f32x16 f = {};
            __builtin_amdgcn_s_setprio(1);
#pragma unroll
            for (int kk = 0; kk < 8; kk++)
                f = MFMA32(av[kk], pf[kk], f);
            __builtin_amdgcn_s_setprio(0);
#pragma unroll
            for (int r = 0; r < 16; r++)
                s += __builtin_amdgcn_exp2f(f[r]);
        }
        __syncthreads();
    }
    s += __shfl_xor(s, 32);
    if (hi == 0)
        ps[isp * NB + bb * N_ + jw] = s;
}

// ---------------- merge: md[j] = -log2(sum_isp ps) ----------------
__global__ void k_colmerge(const float* __restrict__ ps, float* __restrict__ md) {
    int j = blockIdx.x * 256 + threadIdx.x;          // 0..16383
    float s = 0.f;
    for (int isp = 0; isp < ISPLIT; isp++) s += ps[isp * NB + j];
    md[j] = -__log2f(s);
}

// ---------------- pass 3: y = softmax(f) @ g  (swapped-QK 32x32, in-reg softmax) --
// Per block: 4 waves x 32 i-rows = 128 i, one j-quarter (1024 j, 16 tiles of 64).
// QK: facc preloaded with -log2(D) (C-operand), accumulates f2 -> exp2 direct.
// W A-frags built with cvt_pkrtz+permlane32_swap (no LDS round-trip).
__global__ __launch_bounds__(256, 2) void k_attn(
        const f16* __restrict__ thetaT, const f16* __restrict__ phiT,
        const f16* __restrict__ gC, const float* __restrict__ md,
        f16* __restrict__ yP) {
    __shared__ __align__(16) char smem[65536];
    f16 (*phiS)[64 * 128] = (f16(*)[64 * 128])smem;            // 2 x 16 KB [j][ci]
    f16 (*gS)[128 * 64]   = (f16(*)[128 * 64])(smem + 32768);  // 2 x 16 KB [ci][j]
    f16* yTr = (f16*)smem;                                     // epilogue overlay

    int jq = blockIdx.x & 3;
    int ib = blockIdx.x >> 2;          // 0..127
    int bb = ib >> 5;
    int i0 = (ib & 31) * 128;
    int t = threadIdx.x, w = t >> 6, l = t & 63;
    int l31 = l & 31, hi = l >> 5;
    int jbase = jq * 1024;

    // theta B-fragments (K=128 -> 8 kk of 16): B[n=i][k]; lane n=l31, k=hi*8+e
    f16x8 ta[8];
    const f16* tb = thetaT + ((size_t)bb * N_ + i0 + w * 32 + l31) * CI + hi * 8;
#pragma unroll
    for (int kk = 0; kk < 8; kk++)
        ta[kk] = *reinterpret_cast<const f16x8*>(tb + kk * 16);

    const f16* phiB = phiT + (size_t)bb * N_ * CI;
    const f16* gB   = gC   + (size_t)bb * CI * N_;
    const float* mdb = md + bb * N_;

    auto stage = [&](int bf, int j0g) {
#pragma unroll
        for (int r = 0; r < 4; r++) {
            int p = r * 256 + w * 64 + l;
            int ub = (r * 256 + w * 64) * 8;          // wave-uniform LDS base (f16)
            int pj = p >> 4, pu = (p & 15) ^ (pj & 15);
            const char* ga = (const char*)(phiB + (size_t)(j0g + pj) * CI) + pu * 16;
            GLD16(ga, &phiS[bf][ub]);
            int pc = p >> 3, pu2 = (p & 7) ^ (pc & 7);
            const char* ga2 = (const char*)(gB + (size_t)pc * N_ + j0g) + pu2 * 16;
            GLD16(ga2, &gS[bf][ub]);
        }
    };

    f32x16 yacc[4] = {};                 // [cs]: y[i 32][ci = cs*32+l31]
    stage(0, jbase);
    __syncthreads();
    for (int jt = 0; jt < 16; jt++) {
        int bf = jt & 1;
        if (jt + 1 < 16) stage(bf ^ 1, jbase + (jt + 1) * 64);

        // facc init = -log2(D) for this tile's j rows (fold softmax sub into C)
        f32x16 facc[2];
#pragma unroll
        for (int js = 0; js < 2; js++)
#pragma unroll
            for (int c = 0; c < 4; c++) {
                float4 v = *reinterpret_cast<const float4*>(
                    mdb + jbase + jt * 64 + js * 32 + c * 8 + hi * 4);
                facc[js][c * 4 + 0] = v.x; facc[js][c * 4 + 1] = v.y;
                facc[js][c * 4 + 2] = v.z; facc[js][c * 4 + 3] = v.w;
            }

        // QK: facc[js][r] = f2[i=l31][j] - log2 D[j],  j = js*32+(r&3)+8(r>>2)+4hi
        __builtin_amdgcn_s_setprio(1);
#pragma unroll
        for (int kk = 0; kk < 8; kk++) {
#pragma unroll
            for (int js = 0; js < 2; js++) {
                f16x8 pv = *reinterpret_cast<const f16x8*>(
                    &phiS[bf][(js * 32 + l31) * 128 + (((kk * 2 + hi) ^ (l31 & 15)) * 8)]);
                facc[js] = MFMA32(pv, ta[kk], facc[js]);
            }
        }
        __builtin_amdgcn_s_setprio(0);

        // softmax (exp2 direct) + in-register relayout to PV A-frags, then PV
#pragma unroll
        for (int js = 0; js < 2; js++) {
#pragma unroll
            for (int ch = 0; ch < 2; ch++) {
                float e0 = __builtin_amdgcn_exp2f(facc[js][ch * 8 + 0]);
                float e1 = __builtin_amdgcn_exp2f(facc[js][ch * 8 + 1]);
                float e2 = __builtin_amdgcn_exp2f(facc[js][ch * 8 + 2]);
                float e3 = __builtin_amdgcn_exp2f(facc[js][ch * 8 + 3]);
                float e4 = __builtin_amdgcn_exp2f(facc[js][ch * 8 + 4]);
                float e5 = __builtin_amdgcn_exp2f(facc[js][ch * 8 + 5]);
                float e6 = __builtin_amdgcn_exp2f(facc[js][ch * 8 + 6]);
                float e7 = __builtin_amdgcn_exp2f(facc[js][ch * 8 + 7]);
                unsigned p01 = __builtin_bit_cast(unsigned, __builtin_amdgcn_cvt_pkrtz(e0, e1));
                unsigned p23 = __builtin_bit_cast(unsigned, __builtin_amdgcn_cvt_pkrtz(e2, e3));
                unsigned p45 = __builtin_bit_cast(unsigned, __builtin_amdgcn_cvt_pkrtz(e4, e5));
                unsigned p67 = __builtin_bit_cast(unsigned, __builtin_amdgcn_cvt_pkrtz(e6, e7));
                u32x2 s0 = __builtin_amdgcn_permlane32_swap(p01, p45, false, false);
                u32x2 s1 = __builtin_amdgcn_permlane32_swap(p23, p67, false, false);
                u32x4v wu = {s0[0], s1[0], s0[1], s1[1]};
                f16x8 wfr = __builtin_bit_cast(f16x8, wu);   // A[m=i=l31][k=hi*8+e]
                int jc = js * 2 + ch;                        // 16-j chunk index
                __builtin_amdgcn_s_setprio(1);
#pragma unroll
                for (int cs = 0; cs < 4; cs++) {
                    f16x8 gv = *reinterpret_cast<const f16x8*>(
                        &gS[bf][(cs * 32 + l31) * 64 + (((jc * 2 + hi) ^ (l31 & 7)) * 8)]);
                    yacc[cs] = MFMA32(wfr, gv, yacc[cs]);
                }
                __builtin_amdgcn_s_setprio(0);
            }
        }
        __syncthreads();
    }

    // epilogue: yacc[cs][r] = y[i=(r&3)+8*(r>>2)+4*hi][ci=cs*32+l31]
    f16* yw = yTr + w * (32 * 136);
#pragma unroll
    for (int cs = 0; cs < 4; cs++)
#pragma unroll
        for (int r = 0; r < 16; r++)
            yw[((r & 3) + 8 * (r >> 2) + 4 * hi) * 136 + cs * 32 + l31] = (f16)yacc[cs][r];
    f16* yo = yP + (size_t)jq * PSZ + ((size_t)bb * N_ + i0 + w * 32) * CI;
#pragma unroll
    for (int rr = 0; rr < 8; rr++) {
        int chunk = rr * 64 + l;
        int il = chunk >> 4, u = chunk & 15;
        *reinterpret_cast<f16x8*>(yo + il * CI + u * 8) =
            *reinterpret_cast<const f16x8*>(&yw[il * 136 + u * 8]);
    }
}

// ---------------- pass 4: w_y = wz @ (sum of y partials) + b ----------------
// grid 256: block = bb(4) x nb(64 n-tiles of 64); reads its yP slice ONCE,
// computes all 256 output channels; per-block channel partials -> psum.
__global__ __launch_bounds__(256) void k_wz(
        const f16* __restrict__ wzc, const f16* __restrict__ yP,
        const float* __restrict__ zb, f16* __restrict__ wy,
        float* __restrict__ psum) {
    int id = blockIdx.x;                  // 256
    int nb = id & 63, bb = id >> 6;
    int t = threadIdx.x, w = t >> 6, l16 = t & 15, q = (t & 63) >> 4;
    int o0 = w * 64, n0 = nb * 64;
    f32x4 acc[4][4] = {};                 // [os][nt]
#pragma unroll
    for (int kk = 0; kk < 4; kk++) {
        f16x8 bv[4];
#pragma unroll
        for (int nt = 0; nt < 4; nt++) {
            size_t yi = ((size_t)bb * N_ + n0 + nt * 16 + l16) * CI + kk * 32 + q * 8;
            f16x8 b0 = *reinterpret_cast<const f16x8*>(yP + yi);
            f16x8 b1 = *reinterpret_cast<const f16x8*>(yP + PSZ + yi);
            f16x8 b2 = *reinterpret_cast<const f16x8*>(yP + 2 * PSZ + yi);
            f16x8 b3 = *reinterpret_cast<const f16x8*>(yP + 3 * PSZ + yi);
            bv[nt] = (b0 + b1) + (b2 + b3);
        }
#pragma unroll
        for (int os = 0; os < 4; os++) {
            f16x8 av = *reinterpret_cast<const f16x8*>(
                wzc + (o0 + os * 16 + l16) * CI + kk * 32 + q * 8);
#pragma unroll
            for (int nt = 0; nt < 4; nt++)
                acc[os][nt] = MFMA(av, bv[nt], acc[os][nt]);
        }
    }
#pragma unroll
    for (int os = 0; os < 4; os++)
#pragma unroll
    for (int r = 0; r < 4; r++) {
        int o = o0 + os * 16 + q * 4 + r;
        float bias = zb[o];
        float sr = 0.f, qr = 0.f;
#pragma unroll
        for (int nt = 0; nt < 4; nt++) {
            float v = acc[os][nt][r] + bias;
            wy[((size_t)bb * C_ + o) * N_ + n0 + nt * 16 + l16] = (f16)v;
            sr += v; qr += v * v;
        }
#pragma unroll
        for (int off = 1; off < 16; off <<= 1) {
            sr += __shfl_xor(sr, off);
            qr += __shfl_xor(qr, off);
        }
        if (l16 == 0) {
            psum[(o * 2 + 0) * 256 + id] = sr;
            psum[(o * 2 + 1) * 256 + id] = qr;
        }
    }
}

// ---------------- reduce psum -> ssum/ssq ----------------
__global__ void k_red(const float* __restrict__ psum, float* __restrict__ ssum,
                      float* __restrict__ ssq) {
    int b = blockIdx.x;                   // 0: ssum, 1: ssq
    int o = threadIdx.x;
    const float* src = psum + (o * 2 + b) * 256;
    float s = 0.f;
    for (int k = 0; k < 64; k++) {
        float4 v = reinterpret_cast<const float4*>(src)[k];
        s += v.x + v.y + v.z + v.w;
    }
    (b == 0 ? ssum : ssq)[o] = s;
}

// ---------------- pass 5: BN (stats inline) + residual ----------------
__global__ void k_final(const f16* __restrict__ wy, const float* __restrict__ x,
                        const float* __restrict__ ssum, const float* __restrict__ ssq,
                        const float* __restrict__ gamma, const float* __restrict__ beta,
                        float* __restrict__ out) {
    int p = blockIdx.x * 256 + threadIdx.x;           // 512K groups of 8
    int c = (p >> 9) & 255;
    const float inv = 1.0f / 16384.0f;
    float mean = ssum[c] * inv;
    float var = ssq[c] * inv - mean * mean;
    float s = gamma[c] * rsqrtf(var + 1e-5f);
    float h = beta[c] - mean * s;
    f16x8 wv = reinterpret_cast<const f16x8*>(wy)[p];
    float4 x0 = reinterpret_cast<const float4*>(x)[2 * p];
    float4 x1 = reinterpret_cast<const float4*>(x)[2 * p + 1];
    float4 o0, o1;
    o0.x = (float)wv[0] * s + h + x0.x;
    o0.y = (float)wv[1] * s + h + x0.y;
    o0.z = (float)wv[2] * s + h + x0.z;
    o0.w = (float)wv[3] * s + h + x0.w;
    o1.x = (float)wv[4] * s + h + x1.x;
    o1.y = (float)wv[5] * s + h + x1.y;
    o1.z = (float)wv[6] * s + h + x1.z;
    o1.w = (float)wv[7] * s + h + x1.w;
    reinterpret_cast<float4*>(out)[2 * p] = o0;
    reinterpret_cast<float4*>(out)[2 * p + 1] = o1;
}

extern "C" void kernel_launch(void* const* d_in, const int* in_sizes, int n_in,
                              void* d_out, int out_size, void* d_ws, size_t ws_size,
                              hipStream_t stream) {
    const float* x     = (const float*)d_in[0];
    const float* gw    = (const float*)d_in[1];
    const float* gb    = (const float*)d_in[2];
    const float* tw    = (const float*)d_in[3];
    const float* tbv   = (const float*)d_in[4];
    const float* pw    = (const float*)d_in[5];
    const float* pb    = (const float*)d_in[6];
    const float* zw    = (const float*)d_in[7];
    const float* zb    = (const float*)d_in[8];
    const float* gamma = (const float*)d_in[9];
    const float* beta  = (const float*)d_in[10];

    char* ws = (char*)d_ws;
    f16* thetaT = (f16*)(ws + OFF_THETA);
    f16* phiT   = (f16*)(ws + OFF_PHI);
    f16* gC     = (f16*)(ws + OFF_G);
    f16* yP     = (f16*)(ws + OFF_YP);
    f16* wy     = (f16*)(ws + OFF_WY);
    f16* wcvt   = (f16*)(ws + OFF_WCVT);
    float* md   = (float*)(ws + OFF_MD);
    float* ps   = (float*)(ws + OFF_PS);
    float* psum = (float*)(ws + OFF_PSUM);
    float* ssum = (float*)(ws + OFF_SSUM);
    float* ssq  = (float*)(ws + OFF_SSQ);

    k_init<<<512, 256, 0, stream>>>(gw, tw, pw, zw, wcvt);
    k_proj<<<512, 256, 0, stream>>>(x, wcvt, gb, tbv, pb, thetaT, phiT, gC);
    k_cols<<<2048, 256, 0, stream>>>(thetaT, phiT, ps);
    k_colmerge<<<64, 256, 0, stream>>>(ps, md);
    k_attn<<<512, 256, 0, stream>>>(thetaT, phiT, gC, md, yP);
    k_wz<<<256, 256, 0, stream>>>(wcvt + 3 * 32768, yP, zb, wy, psum);
    k_red<<<2, 256, 0, stream>>>(psum, ssum, ssq);
    k_final<<<2048, 256, 0, stream>>>(wy, x, ssum, ssq, gamma, beta, (float*)d_out);
}